// Round 5
// baseline (259.733 us; speedup 1.0000x reference)
//
#include <hip/hip_runtime.h>
#include <math.h>

#define BB 256
#define KK 256
#define VV 256
#define MM 4000
#define TOPK 8

// K1: fused independent prep:
//   blocks [0, MM)      : kn64[m] = normalize(A[midx[m], :, 0])      (r2 verbatim)
//   blocks [MM, MM+BB)  : e64/qn64 from tanh(qk @ Wk^T + bk)         (r2 verbatim)
__global__ void __launch_bounds__(256) k_prep(
        const float* __restrict__ qk, const float* __restrict__ Wk,
        const float* __restrict__ bk, const float* __restrict__ A,
        const int* __restrict__ midx, double* __restrict__ e64,
        double* __restrict__ qn64, double* __restrict__ kn64) {
    __shared__ double red[256];
    __shared__ float q[KK];
    if (blockIdx.x < MM) {
        int m = blockIdx.x, t = threadIdx.x;
        size_t n = (size_t)midx[m];
        double val = (double)A[n * (size_t)(KK * VV) + (size_t)t * VV];
        red[t] = val * val;
        __syncthreads();
        for (int s = 128; s > 0; s >>= 1) {
            if (t < s) red[t] += red[t + s];
            __syncthreads();
        }
        double nrm = fmax(sqrt(red[0]), 1e-8);
        kn64[(size_t)m * KK + t] = val / nrm;
    } else {
        int b = blockIdx.x - MM, j = threadIdx.x;
        q[j] = qk[b * KK + j];
        __syncthreads();
        const float* w = Wk + (size_t)j * KK;
        double acc = 0.0;
#pragma unroll 4
        for (int d = 0; d < KK; ++d) acc += (double)q[d] * (double)w[d];
        double val = tanh(acc + (double)bk[j]);
        e64[b * KK + j] = val;
        red[j] = val * val;
        __syncthreads();
        for (int s = 128; s > 0; s >>= 1) {
            if (j < s) red[j] += red[j + s];
            __syncthreads();
        }
        double nrm = fmax(sqrt(red[0]), 1e-8);
        qn64[b * KK + j] = val / nrm;
    }
}

// K3: sims64 = qn64 @ kn64^T (B x M), f64, 32x32 tile, 2x2 register blocking.
// (verbatim from round-4 PASSED kernel)
__global__ void __launch_bounds__(256) k_sims(
        const double* __restrict__ qn, const double* __restrict__ kn,
        double* __restrict__ sims) {
    int tx = threadIdx.x, ty = threadIdx.y;   // 16x16
    int tid = ty * 16 + tx;
    int m0 = blockIdx.x * 32, b0 = blockIdx.y * 32;
    __shared__ double qs[32][33], ks[32][33];
    double a00 = 0.0, a01 = 0.0, a10 = 0.0, a11 = 0.0;
    for (int kk = 0; kk < KK; kk += 32) {
#pragma unroll
        for (int i = 0; i < 4; ++i) {
            int idx = tid + i * 256;          // 0..1023
            int r = idx >> 5, c = idx & 31;
            qs[r][c] = qn[(size_t)(b0 + r) * KK + kk + c];
            ks[r][c] = kn[(size_t)(m0 + r) * KK + kk + c];
        }
        __syncthreads();
#pragma unroll
        for (int i = 0; i < 32; ++i) {
            double q0 = qs[ty][i], q1 = qs[ty + 16][i];
            double k0 = ks[tx][i], k1 = ks[tx + 16][i];
            a00 += q0 * k0; a01 += q0 * k1;
            a10 += q1 * k0; a11 += q1 * k1;
        }
        __syncthreads();
    }
    sims[(size_t)(b0 + ty) * MM + m0 + tx]           = a00;
    sims[(size_t)(b0 + ty) * MM + m0 + tx + 16]      = a01;
    sims[(size_t)(b0 + ty + 16) * MM + m0 + tx]      = a10;
    sims[(size_t)(b0 + ty + 16) * MM + m0 + tx + 16] = a11;
}

// K4: per-row top-8 (value desc, stable by index) in f64 + confidences
// (verbatim from round-2 PASSED kernel)
__global__ void k_topk(const double* __restrict__ sims, const int* __restrict__ midx,
                       const float* __restrict__ usage, float* __restrict__ out_conf,
                       float* __restrict__ out_sims, int* __restrict__ acts) {
    int b = blockIdx.x, t = threadIdx.x;
    double v[TOPK];
    int id[TOPK];
#pragma unroll
    for (int i = 0; i < TOPK; ++i) { v[i] = -INFINITY; id[i] = 0x7fffffff; }
    const double* row = sims + (size_t)b * MM;
    for (int m = t; m < MM; m += 256) {
        double x = row[m];
        if (x > v[TOPK - 1]) {
            v[TOPK - 1] = x; id[TOPK - 1] = m;
#pragma unroll
            for (int i = TOPK - 1; i > 0; --i) {
                if (v[i] > v[i - 1]) {  // strict: equal values keep smaller index first
                    double tv = v[i]; v[i] = v[i - 1]; v[i - 1] = tv;
                    int ti = id[i]; id[i] = id[i - 1]; id[i - 1] = ti;
                }
            }
        }
    }
    __shared__ double sv[256 * TOPK];
    __shared__ int si[256 * TOPK];
#pragma unroll
    for (int i = 0; i < TOPK; ++i) { sv[t * TOPK + i] = v[i]; si[t * TOPK + i] = id[i]; }
    __syncthreads();
    for (int stride = 128; stride > 0; stride >>= 1) {
        if (t < stride) {
            double* av = &sv[t * TOPK];
            int*    ai = &si[t * TOPK];
            double* bv = &sv[(t + stride) * TOPK];
            int*    bi = &si[(t + stride) * TOPK];
            double mv[TOPK]; int mi[TOPK];
            int pa = 0, pb = 0;
#pragma unroll
            for (int i = 0; i < TOPK; ++i) {
                double va = av[pa], vb = bv[pb];
                bool takeA = (va > vb) || (va == vb && ai[pa] < bi[pb]);
                if (takeA) { mv[i] = va; mi[i] = ai[pa]; ++pa; }
                else       { mv[i] = vb; mi[i] = bi[pb]; ++pb; }
            }
#pragma unroll
            for (int i = 0; i < TOPK; ++i) { av[i] = mv[i]; ai[i] = mi[i]; }
        }
        __syncthreads();
    }
    if (t < TOPK) {
        double val = sv[t];
        int idx = si[t];
        int actual = midx[idx];
        out_sims[b * TOPK + t] = (float)val;
        out_conf[b * TOPK + t] = (float)(val * (1.0 + log1p((double)usage[actual])));
        acts[b * TOPK + t] = actual;
    }
}

// K4b: sort the 2048 (n, slot) pairs by n so duplicate/nearby gathered rows
// land in temporally adjacent blocks of k_retr (L2/L3 hits instead of HBM).
// Single block, bitonic sort on packed keys (n<<11 | slot). Deterministic.
__global__ void __launch_bounds__(256) k_sort(const int* __restrict__ acts,
                                              unsigned* __restrict__ sorted) {
    __shared__ unsigned key[BB * TOPK];
    int t = threadIdx.x;
    for (int i = t; i < BB * TOPK; i += 256)
        key[i] = ((unsigned)acts[i] << 11) | (unsigned)i;
    __syncthreads();
    for (int k = 2; k <= BB * TOPK; k <<= 1) {
        for (int j = k >> 1; j > 0; j >>= 1) {
            for (int i = t; i < BB * TOPK; i += 256) {
                int l = i ^ j;
                if (l > i) {
                    bool asc = ((i & k) == 0);
                    unsigned a = key[i], b2 = key[l];
                    bool sw = asc ? (a > b2) : (a < b2);
                    if (sw) { key[i] = b2; key[l] = a; }
                }
            }
            __syncthreads();
        }
    }
    for (int i = t; i < BB * TOPK; i += 256) sorted[i] = key[i];
}

// K5: retrieved[slot, v] = sum_d e[b,d] * A[n, d, v], slot/n from sorted key.
// float4 loads, 4 waves split the d-range, LDS reduce. (r4 PASSED structure;
// only the block->row indirection changed.)
__global__ void __launch_bounds__(256) k_retr(
        const float* __restrict__ A, const double* __restrict__ e64,
        const unsigned* __restrict__ sorted, float* __restrict__ out) {
    unsigned keyv = sorted[blockIdx.x];
    int bk_ = (int)(keyv & 0x7FFu);  // original slot = b*TOPK + k
    size_t n = (size_t)(keyv >> 11);
    int b = bk_ >> 3;
    int tid = threadIdx.x;
    int w = tid >> 6, l = tid & 63;
    const float* Ap = A + n * (size_t)(KK * VV);
    __shared__ float es[KK];
    __shared__ float part[4][64][4];
    es[tid] = (float)e64[b * KK + tid];
    __syncthreads();
    float ax = 0.f, ay = 0.f, az = 0.f, aw = 0.f;
    const float* base = Ap + (size_t)(w * 64) * VV + 4 * l;
#pragma unroll 8
    for (int dd = 0; dd < 64; ++dd) {
        float ev = es[w * 64 + dd];
        const float4 a = *reinterpret_cast<const float4*>(base + (size_t)dd * VV);
        ax = fmaf(ev, a.x, ax); ay = fmaf(ev, a.y, ay);
        az = fmaf(ev, a.z, az); aw = fmaf(ev, a.w, aw);
    }
    part[w][l][0] = ax; part[w][l][1] = ay; part[w][l][2] = az; part[w][l][3] = aw;
    __syncthreads();
    int l2 = tid >> 2, j = tid & 3;
    float s = part[0][l2][j] + part[1][l2][j] + part[2][l2][j] + part[3][l2][j];
    out[(size_t)bk_ * VV + tid] = s;
}

extern "C" void kernel_launch(void* const* d_in, const int* in_sizes, int n_in,
                              void* d_out, int out_size, void* d_ws, size_t ws_size,
                              hipStream_t stream) {
    const float* qk    = (const float*)d_in[0];
    const float* Wk    = (const float*)d_in[1];
    const float* bk    = (const float*)d_in[2];
    const float* A     = (const float*)d_in[3];
    const float* usage = (const float*)d_in[4];
    const int*   midx  = (const int*)d_in[5];

    float* out   = (float*)d_out;
    float* retr  = out;                                 // B*TOPK*V = 524288
    float* conf  = out + (size_t)BB * TOPK * VV;        // 2048
    float* tsims = conf + BB * TOPK;                    // 2048

    // workspace layout: r2/r4 PASSED layout + sorted keys at the end
    double*   ws64   = (double*)d_ws;
    double*   e64    = ws64;                               // 65536 doubles
    double*   qn64   = e64 + BB * KK;                      // 65536
    double*   kn64   = qn64 + BB * KK;                     // 1,024,000
    double*   sims   = kn64 + (size_t)MM * KK;             // 1,024,000
    int*      acts   = (int*)(sims + (size_t)BB * MM);     // 2048 ints
    unsigned* sorted = (unsigned*)(acts + BB * TOPK);      // 2048 uints

    k_prep<<<MM + BB, 256, 0, stream>>>(qk, Wk, bk, A, midx, e64, qn64, kn64);
    dim3 g3(MM / 32, BB / 32), b3(16, 16);
    k_sims<<<g3, b3, 0, stream>>>(qn64, kn64, sims);
    k_topk<<<BB, 256, 0, stream>>>(sims, midx, usage, conf, tsims, acts);
    k_sort<<<1, 256, 0, stream>>>(acts, sorted);
    k_retr<<<BB * TOPK, 256, 0, stream>>>(A, e64, sorted, retr);
}

// Round 6
// 192.058 us; speedup vs baseline: 1.3524x; 1.3524x over previous
//
#include <hip/hip_runtime.h>
#include <math.h>

#define BB 256
#define KK 256
#define VV 256
#define MM 4000
#define TOPK 8

// K1: fused independent prep (bodies verbatim from r2/r4 PASSED kernels):
//   blocks [0, MM)      : kn64[m] = normalize(A[midx[m], :, 0])
//   blocks [MM, MM+BB)  : e64/qn64 from tanh(qk @ Wk^T + bk)
__global__ void __launch_bounds__(256) k_prep(
        const float* __restrict__ qk, const float* __restrict__ Wk,
        const float* __restrict__ bk, const float* __restrict__ A,
        const int* __restrict__ midx, double* __restrict__ e64,
        double* __restrict__ qn64, double* __restrict__ kn64) {
    __shared__ double red[256];
    __shared__ float q[KK];
    if (blockIdx.x < MM) {
        int m = blockIdx.x, t = threadIdx.x;
        size_t n = (size_t)midx[m];
        double val = (double)A[n * (size_t)(KK * VV) + (size_t)t * VV];
        red[t] = val * val;
        __syncthreads();
        for (int s = 128; s > 0; s >>= 1) {
            if (t < s) red[t] += red[t + s];
            __syncthreads();
        }
        double nrm = fmax(sqrt(red[0]), 1e-8);
        kn64[(size_t)m * KK + t] = val / nrm;
    } else {
        int b = blockIdx.x - MM, j = threadIdx.x;
        q[j] = qk[b * KK + j];
        __syncthreads();
        const float* w = Wk + (size_t)j * KK;
        double acc = 0.0;
#pragma unroll 4
        for (int d = 0; d < KK; ++d) acc += (double)q[d] * (double)w[d];
        double val = tanh(acc + (double)bk[j]);
        e64[b * KK + j] = val;
        red[j] = val * val;
        __syncthreads();
        for (int s = 128; s > 0; s >>= 1) {
            if (j < s) red[j] += red[j + s];
            __syncthreads();
        }
        double nrm = fmax(sqrt(red[0]), 1e-8);
        qn64[b * KK + j] = val / nrm;
    }
}

// K3: sims64 = qn64 @ kn64^T (B x M), f64, 32x32 tile, 2x2 register blocking.
// (verbatim from round-4 PASSED kernel)
__global__ void __launch_bounds__(256) k_sims(
        const double* __restrict__ qn, const double* __restrict__ kn,
        double* __restrict__ sims) {
    int tx = threadIdx.x, ty = threadIdx.y;   // 16x16
    int tid = ty * 16 + tx;
    int m0 = blockIdx.x * 32, b0 = blockIdx.y * 32;
    __shared__ double qs[32][33], ks[32][33];
    double a00 = 0.0, a01 = 0.0, a10 = 0.0, a11 = 0.0;
    for (int kk = 0; kk < KK; kk += 32) {
#pragma unroll
        for (int i = 0; i < 4; ++i) {
            int idx = tid + i * 256;          // 0..1023
            int r = idx >> 5, c = idx & 31;
            qs[r][c] = qn[(size_t)(b0 + r) * KK + kk + c];
            ks[r][c] = kn[(size_t)(m0 + r) * KK + kk + c];
        }
        __syncthreads();
#pragma unroll
        for (int i = 0; i < 32; ++i) {
            double q0 = qs[ty][i], q1 = qs[ty + 16][i];
            double k0 = ks[tx][i], k1 = ks[tx + 16][i];
            a00 += q0 * k0; a01 += q0 * k1;
            a10 += q1 * k0; a11 += q1 * k1;
        }
        __syncthreads();
    }
    sims[(size_t)(b0 + ty) * MM + m0 + tx]           = a00;
    sims[(size_t)(b0 + ty) * MM + m0 + tx + 16]      = a01;
    sims[(size_t)(b0 + ty + 16) * MM + m0 + tx]      = a10;
    sims[(size_t)(b0 + ty + 16) * MM + m0 + tx + 16] = a11;
}

// K4: per-row top-8 (value desc, stable by index) in f64 + confidences
// (verbatim from round-2 PASSED kernel)
__global__ void k_topk(const double* __restrict__ sims, const int* __restrict__ midx,
                       const float* __restrict__ usage, float* __restrict__ out_conf,
                       float* __restrict__ out_sims, int* __restrict__ acts) {
    int b = blockIdx.x, t = threadIdx.x;
    double v[TOPK];
    int id[TOPK];
#pragma unroll
    for (int i = 0; i < TOPK; ++i) { v[i] = -INFINITY; id[i] = 0x7fffffff; }
    const double* row = sims + (size_t)b * MM;
    for (int m = t; m < MM; m += 256) {
        double x = row[m];
        if (x > v[TOPK - 1]) {
            v[TOPK - 1] = x; id[TOPK - 1] = m;
#pragma unroll
            for (int i = TOPK - 1; i > 0; --i) {
                if (v[i] > v[i - 1]) {  // strict: equal values keep smaller index first
                    double tv = v[i]; v[i] = v[i - 1]; v[i - 1] = tv;
                    int ti = id[i]; id[i] = id[i - 1]; id[i - 1] = ti;
                }
            }
        }
    }
    __shared__ double sv[256 * TOPK];
    __shared__ int si[256 * TOPK];
#pragma unroll
    for (int i = 0; i < TOPK; ++i) { sv[t * TOPK + i] = v[i]; si[t * TOPK + i] = id[i]; }
    __syncthreads();
    for (int stride = 128; stride > 0; stride >>= 1) {
        if (t < stride) {
            double* av = &sv[t * TOPK];
            int*    ai = &si[t * TOPK];
            double* bv = &sv[(t + stride) * TOPK];
            int*    bi = &si[(t + stride) * TOPK];
            double mv[TOPK]; int mi[TOPK];
            int pa = 0, pb = 0;
#pragma unroll
            for (int i = 0; i < TOPK; ++i) {
                double va = av[pa], vb = bv[pb];
                bool takeA = (va > vb) || (va == vb && ai[pa] < bi[pb]);
                if (takeA) { mv[i] = va; mi[i] = ai[pa]; ++pa; }
                else       { mv[i] = vb; mi[i] = bi[pb]; ++pb; }
            }
#pragma unroll
            for (int i = 0; i < TOPK; ++i) { av[i] = mv[i]; ai[i] = mi[i]; }
        }
        __syncthreads();
    }
    if (t < TOPK) {
        double val = sv[t];
        int idx = si[t];
        int actual = midx[idx];
        out_sims[b * TOPK + t] = (float)val;
        out_conf[b * TOPK + t] = (float)(val * (1.0 + log1p((double)usage[actual])));
        acts[b * TOPK + t] = actual;
    }
}

// K5: retrieved[b,k,v] = sum_d e[b,d] * A[acts[b,k], d, v]
// float4 loads, 4 waves split the d-range, LDS reduce.
// (verbatim from round-4 PASSED kernel — sort indirection removed)
__global__ void __launch_bounds__(256) k_retr(
        const float* __restrict__ A, const double* __restrict__ e64,
        const int* __restrict__ acts, float* __restrict__ out) {
    int bk_ = blockIdx.x;        // b*TOPK + k
    int b = bk_ >> 3;
    int tid = threadIdx.x;
    int w = tid >> 6, l = tid & 63;
    size_t n = (size_t)acts[bk_];
    const float* Ap = A + n * (size_t)(KK * VV);
    __shared__ float es[KK];
    __shared__ float part[4][64][4];
    es[tid] = (float)e64[b * KK + tid];
    __syncthreads();
    float ax = 0.f, ay = 0.f, az = 0.f, aw = 0.f;
    const float* base = Ap + (size_t)(w * 64) * VV + 4 * l;
#pragma unroll 8
    for (int dd = 0; dd < 64; ++dd) {
        float ev = es[w * 64 + dd];
        const float4 a = *reinterpret_cast<const float4*>(base + (size_t)dd * VV);
        ax = fmaf(ev, a.x, ax); ay = fmaf(ev, a.y, ay);
        az = fmaf(ev, a.z, az); aw = fmaf(ev, a.w, aw);
    }
    part[w][l][0] = ax; part[w][l][1] = ay; part[w][l][2] = az; part[w][l][3] = aw;
    __syncthreads();
    int l2 = tid >> 2, j = tid & 3;
    float s = part[0][l2][j] + part[1][l2][j] + part[2][l2][j] + part[3][l2][j];
    out[(size_t)bk_ * VV + tid] = s;   // 4*l2 + j == tid
}

extern "C" void kernel_launch(void* const* d_in, const int* in_sizes, int n_in,
                              void* d_out, int out_size, void* d_ws, size_t ws_size,
                              hipStream_t stream) {
    const float* qk    = (const float*)d_in[0];
    const float* Wk    = (const float*)d_in[1];
    const float* bk    = (const float*)d_in[2];
    const float* A     = (const float*)d_in[3];
    const float* usage = (const float*)d_in[4];
    const int*   midx  = (const int*)d_in[5];

    float* out   = (float*)d_out;
    float* retr  = out;                                 // B*TOPK*V = 524288
    float* conf  = out + (size_t)BB * TOPK * VV;        // 2048
    float* tsims = conf + BB * TOPK;                    // 2048

    // workspace layout: identical to the r2/r4 PASSED layout
    double* ws64  = (double*)d_ws;
    double* e64   = ws64;                               // 65536 doubles
    double* qn64  = e64 + BB * KK;                      // 65536
    double* kn64  = qn64 + BB * KK;                     // 1,024,000
    double* sims  = kn64 + (size_t)MM * KK;             // 1,024,000
    int*    acts  = (int*)(sims + (size_t)BB * MM);     // 2048 ints

    k_prep<<<MM + BB, 256, 0, stream>>>(qk, Wk, bk, A, midx, e64, qn64, kn64);
    dim3 g3(MM / 32, BB / 32), b3(16, 16);
    k_sims<<<g3, b3, 0, stream>>>(qn64, kn64, sims);
    k_topk<<<BB, 256, 0, stream>>>(sims, midx, usage, conf, tsims, acts);
    k_retr<<<BB * TOPK, 256, 0, stream>>>(A, e64, acts, retr);
}

// Round 7
// 178.617 us; speedup vs baseline: 1.4541x; 1.0753x over previous
//
#include <hip/hip_runtime.h>
#include <math.h>

#define BB 256
#define KK 256
#define VV 256
#define MM 4000
#define TOPK 8

// K1: e64 = tanh(qk @ Wk^T + bk); qn64 = e64 / max(||e64||, 1e-8)
// (verbatim from round-2/4 PASSED kernel; kept SEPARATE from k_kn — r6 showed
// fusing them halves the gather's occupancy via the fat branch's VGPR count)
__global__ void k_proj(const float* __restrict__ qk, const float* __restrict__ Wk,
                       const float* __restrict__ bk, double* __restrict__ e64,
                       double* __restrict__ qn64) {
    int b = blockIdx.x, j = threadIdx.x;
    __shared__ float q[KK];
    __shared__ double red[256];
    q[j] = qk[b * KK + j];
    __syncthreads();
    const float* w = Wk + (size_t)j * KK;
    double acc = 0.0;
#pragma unroll 4
    for (int d = 0; d < KK; ++d) acc += (double)q[d] * (double)w[d];
    double val = tanh(acc + (double)bk[j]);
    e64[b * KK + j] = val;
    red[j] = val * val;
    __syncthreads();
    for (int s = 128; s > 0; s >>= 1) {
        if (j < s) red[j] += red[j + s];
        __syncthreads();
    }
    double nrm = fmax(sqrt(red[0]), 1e-8);
    qn64[b * KK + j] = val / nrm;
}

// K2: gather stored_keys = A[midx[m], k, 0]; kn64 = row / max(||row||, 1e-8)
// (verbatim from round-2/4 PASSED kernel)
__global__ void k_kn(const float* __restrict__ A, const int* __restrict__ midx,
                     double* __restrict__ kn64) {
    int m = blockIdx.x, t = threadIdx.x;
    size_t n = (size_t)midx[m];
    double val = (double)A[n * (size_t)(KK * VV) + (size_t)t * VV];
    __shared__ double red[256];
    red[t] = val * val;
    __syncthreads();
    for (int s = 128; s > 0; s >>= 1) {
        if (t < s) red[t] += red[t + s];
        __syncthreads();
    }
    double nrm = fmax(sqrt(red[0]), 1e-8);
    kn64[(size_t)m * KK + t] = val / nrm;
}

// K3: sims64 = qn64 @ kn64^T (B x M), f64.
// NEW: 32x64 tile, 128 threads, 4x4 register blocking, k-major transposed LDS
// tiles (even pad -> 16B-aligned double2 reads; 0.25 LDS reads per FMA vs 1.0
// in the r4 2x2 version). Per-output accumulation order unchanged (k = 0..255
// sequential, single f64 accumulator) -> sims bit-identical to r4.
#define BMS 32
#define BNS 64
#define KS  16
__global__ void __launch_bounds__(128) k_sims(
        const double* __restrict__ qn, const double* __restrict__ kn,
        double* __restrict__ sims) {
    __shared__ double qsT[KS][BMS + 2];   // [k][b], stride 34 (even, 16B-align)
    __shared__ double ksT[KS][BNS + 2];   // [k][m], stride 66
    int tid = threadIdx.x;                // 0..127
    int tx = tid & 15;                    // m-group (4 cols each)
    int ty = tid >> 4;                    // b-group (4 rows each), 0..7
    int m0 = blockIdx.x * BNS;
    int b0 = blockIdx.y * BMS;
    double acc[4][4] = {};
    // staging maps
    int qr = tid >> 2;                    // 0..31  b-row
    int qc = (tid & 3) * 4;               // k-col group (4 wide)
    int kr = tid >> 1;                    // 0..63  m-row
    int kc = (tid & 1) * 8;               // k-col group (8 wide)
    bool kval = (m0 + kr) < MM;
    const double* qrow = qn + (size_t)(b0 + qr) * KK;
    const double* krow = kn + (size_t)(m0 + (kval ? kr : 0)) * KK;  // clamped addr
    for (int kk = 0; kk < KK; kk += KS) {
#pragma unroll
        for (int j = 0; j < 4; ++j)
            qsT[qc + j][qr] = qrow[kk + qc + j];
#pragma unroll
        for (int j = 0; j < 8; ++j)
            ksT[kc + j][kr] = kval ? krow[kk + kc + j] : 0.0;
        __syncthreads();
#pragma unroll
        for (int i = 0; i < KS; ++i) {
            double qv[4], kv[4];
            *(double2*)&qv[0] = *(const double2*)&qsT[i][ty * 4];
            *(double2*)&qv[2] = *(const double2*)&qsT[i][ty * 4 + 2];
            *(double2*)&kv[0] = *(const double2*)&ksT[i][tx * 4];
            *(double2*)&kv[2] = *(const double2*)&ksT[i][tx * 4 + 2];
#pragma unroll
            for (int a = 0; a < 4; ++a)
#pragma unroll
                for (int c = 0; c < 4; ++c)
                    acc[a][c] += qv[a] * kv[c];
        }
        __syncthreads();
    }
#pragma unroll
    for (int a = 0; a < 4; ++a) {
        int bb = b0 + ty * 4 + a;
#pragma unroll
        for (int c = 0; c < 4; ++c) {
            int mm2 = m0 + tx * 4 + c;
            if (mm2 < MM) sims[(size_t)bb * MM + mm2] = acc[a][c];
        }
    }
}

// K4: per-row top-8 (value desc, stable by index) in f64 + confidences
// (verbatim from round-2 PASSED kernel)
__global__ void k_topk(const double* __restrict__ sims, const int* __restrict__ midx,
                       const float* __restrict__ usage, float* __restrict__ out_conf,
                       float* __restrict__ out_sims, int* __restrict__ acts) {
    int b = blockIdx.x, t = threadIdx.x;
    double v[TOPK];
    int id[TOPK];
#pragma unroll
    for (int i = 0; i < TOPK; ++i) { v[i] = -INFINITY; id[i] = 0x7fffffff; }
    const double* row = sims + (size_t)b * MM;
    for (int m = t; m < MM; m += 256) {
        double x = row[m];
        if (x > v[TOPK - 1]) {
            v[TOPK - 1] = x; id[TOPK - 1] = m;
#pragma unroll
            for (int i = TOPK - 1; i > 0; --i) {
                if (v[i] > v[i - 1]) {  // strict: equal values keep smaller index first
                    double tv = v[i]; v[i] = v[i - 1]; v[i - 1] = tv;
                    int ti = id[i]; id[i] = id[i - 1]; id[i - 1] = ti;
                }
            }
        }
    }
    __shared__ double sv[256 * TOPK];
    __shared__ int si[256 * TOPK];
#pragma unroll
    for (int i = 0; i < TOPK; ++i) { sv[t * TOPK + i] = v[i]; si[t * TOPK + i] = id[i]; }
    __syncthreads();
    for (int stride = 128; stride > 0; stride >>= 1) {
        if (t < stride) {
            double* av = &sv[t * TOPK];
            int*    ai = &si[t * TOPK];
            double* bv = &sv[(t + stride) * TOPK];
            int*    bi = &si[(t + stride) * TOPK];
            double mv[TOPK]; int mi[TOPK];
            int pa = 0, pb = 0;
#pragma unroll
            for (int i = 0; i < TOPK; ++i) {
                double va = av[pa], vb = bv[pb];
                bool takeA = (va > vb) || (va == vb && ai[pa] < bi[pb]);
                if (takeA) { mv[i] = va; mi[i] = ai[pa]; ++pa; }
                else       { mv[i] = vb; mi[i] = bi[pb]; ++pb; }
            }
#pragma unroll
            for (int i = 0; i < TOPK; ++i) { av[i] = mv[i]; ai[i] = mi[i]; }
        }
        __syncthreads();
    }
    if (t < TOPK) {
        double val = sv[t];
        int idx = si[t];
        int actual = midx[idx];
        out_sims[b * TOPK + t] = (float)val;
        out_conf[b * TOPK + t] = (float)(val * (1.0 + log1p((double)usage[actual])));
        acts[b * TOPK + t] = actual;
    }
}

// K5: retrieved[b,k,v] = sum_d e[b,d] * A[acts[b,k], d, v]
// float4 loads, 4 waves split the d-range, LDS reduce.
// (verbatim from round-4 PASSED kernel)
__global__ void __launch_bounds__(256) k_retr(
        const float* __restrict__ A, const double* __restrict__ e64,
        const int* __restrict__ acts, float* __restrict__ out) {
    int bk_ = blockIdx.x;        // b*TOPK + k
    int b = bk_ >> 3;
    int tid = threadIdx.x;
    int w = tid >> 6, l = tid & 63;
    size_t n = (size_t)acts[bk_];
    const float* Ap = A + n * (size_t)(KK * VV);
    __shared__ float es[KK];
    __shared__ float part[4][64][4];
    es[tid] = (float)e64[b * KK + tid];
    __syncthreads();
    float ax = 0.f, ay = 0.f, az = 0.f, aw = 0.f;
    const float* base = Ap + (size_t)(w * 64) * VV + 4 * l;
#pragma unroll 8
    for (int dd = 0; dd < 64; ++dd) {
        float ev = es[w * 64 + dd];
        const float4 a = *reinterpret_cast<const float4*>(base + (size_t)dd * VV);
        ax = fmaf(ev, a.x, ax); ay = fmaf(ev, a.y, ay);
        az = fmaf(ev, a.z, az); aw = fmaf(ev, a.w, aw);
    }
    part[w][l][0] = ax; part[w][l][1] = ay; part[w][l][2] = az; part[w][l][3] = aw;
    __syncthreads();
    int l2 = tid >> 2, j = tid & 3;
    float s = part[0][l2][j] + part[1][l2][j] + part[2][l2][j] + part[3][l2][j];
    out[(size_t)bk_ * VV + tid] = s;   // 4*l2 + j == tid
}

extern "C" void kernel_launch(void* const* d_in, const int* in_sizes, int n_in,
                              void* d_out, int out_size, void* d_ws, size_t ws_size,
                              hipStream_t stream) {
    const float* qk    = (const float*)d_in[0];
    const float* Wk    = (const float*)d_in[1];
    const float* bk    = (const float*)d_in[2];
    const float* A     = (const float*)d_in[3];
    const float* usage = (const float*)d_in[4];
    const int*   midx  = (const int*)d_in[5];

    float* out   = (float*)d_out;
    float* retr  = out;                                 // B*TOPK*V = 524288
    float* conf  = out + (size_t)BB * TOPK * VV;        // 2048
    float* tsims = conf + BB * TOPK;                    // 2048

    // workspace layout: identical to the r2/r4 PASSED layout
    double* ws64  = (double*)d_ws;
    double* e64   = ws64;                               // 65536 doubles
    double* qn64  = e64 + BB * KK;                      // 65536
    double* kn64  = qn64 + BB * KK;                     // 1,024,000
    double* sims  = kn64 + (size_t)MM * KK;             // 1,024,000
    int*    acts  = (int*)(sims + (size_t)BB * MM);     // 2048 ints

    k_proj<<<BB, 256, 0, stream>>>(qk, Wk, bk, e64, qn64);
    k_kn<<<MM, 256, 0, stream>>>(A, midx, kn64);
    dim3 g3((MM + BNS - 1) / BNS, BB / BMS);            // 63 x 8
    k_sims<<<g3, 128, 0, stream>>>(qn64, kn64, sims);
    k_topk<<<BB, 256, 0, stream>>>(sims, midx, usage, conf, tsims, acts);
    k_retr<<<BB * TOPK, 256, 0, stream>>>(A, e64, acts, retr);
}

// Round 9
// 174.307 us; speedup vs baseline: 1.4901x; 1.0247x over previous
//
#include <hip/hip_runtime.h>
#include <math.h>

#define BB 256
#define KK 256
#define VV 256
#define MM 4000
#define TOPK 8

// K1: e64 = tanh(qk @ Wk^T + bk); qn64 = e64 / max(||e64||, 1e-8)
// (verbatim from round-2/4 PASSED kernel)
__global__ void k_proj(const float* __restrict__ qk, const float* __restrict__ Wk,
                       const float* __restrict__ bk, double* __restrict__ e64,
                       double* __restrict__ qn64) {
    int b = blockIdx.x, j = threadIdx.x;
    __shared__ float q[KK];
    __shared__ double red[256];
    q[j] = qk[b * KK + j];
    __syncthreads();
    const float* w = Wk + (size_t)j * KK;
    double acc = 0.0;
#pragma unroll 4
    for (int d = 0; d < KK; ++d) acc += (double)q[d] * (double)w[d];
    double val = tanh(acc + (double)bk[j]);
    e64[b * KK + j] = val;
    red[j] = val * val;
    __syncthreads();
    for (int s = 128; s > 0; s >>= 1) {
        if (j < s) red[j] += red[j + s];
        __syncthreads();
    }
    double nrm = fmax(sqrt(red[0]), 1e-8);
    qn64[b * KK + j] = val / nrm;
}

// K2: gather stored_keys = A[midx[m], k, 0]; kn64 = row / max(||row||, 1e-8)
// (verbatim from round-2/4 PASSED kernel)
__global__ void k_kn(const float* __restrict__ A, const int* __restrict__ midx,
                     double* __restrict__ kn64) {
    int m = blockIdx.x, t = threadIdx.x;
    size_t n = (size_t)midx[m];
    double val = (double)A[n * (size_t)(KK * VV) + (size_t)t * VV];
    __shared__ double red[256];
    red[t] = val * val;
    __syncthreads();
    for (int s = 128; s > 0; s >>= 1) {
        if (t < s) red[t] += red[t + s];
        __syncthreads();
    }
    double nrm = fmax(sqrt(red[0]), 1e-8);
    kn64[(size_t)m * KK + t] = val / nrm;
}

// K3 v3b: sims64 = qn64 @ kn64^T, f64. 16x64 tile, ONE wave (64 thr), 4x4 per
// thread, double-buffered LDS with async-stage split (loads->regs early, LDS
// writes late). SKEW FIX vs r8: stride 72, p(m) = m + (m>>4)*2 — bijective
// (16-groups land at [0..15],[18..33],[36..51],[54..69]; r8's masked skew
// collided at m=30,31 vs 32,33 and corrupted sims -> wrong top-k).
// Per-accumulator k-order = sequential 0..255 => sims bit-identical to r4.
#define BMS 16
#define BNS 64
#define KS  16
__global__ void __launch_bounds__(64) k_sims(
        const double* __restrict__ qn, const double* __restrict__ kn,
        double* __restrict__ sims) {
    __shared__ double qsT[2][KS][BMS + 2];   // [buf][k][b-row], stride 18 (144B, 16B-aligned)
    __shared__ double ksT[2][KS][BNS + 8];   // [buf][k][m-skewed], stride 72 (576B, 16B-aligned)
    int tid = threadIdx.x;
    int tx = tid & 15, ty = tid >> 4;        // tx: m-group (4 cols), ty: b-group (4 rows)
    int m0 = blockIdx.x * BNS, b0 = blockIdx.y * BMS;
    // staging maps
    int qr = tid & 15;                       // b-row
    int qc = (tid >> 4) * 4;                 // k-col base (4 wide)
    int krr = tid >> 3;                      // m-row base (0..7), +8*s
    int kc = (tid & 7) * 2;                  // k-col (double2)
    const double* qrow = qn + (size_t)(b0 + qr) * KK;
    double acc[4][4] = {};
    // bijective skew: p(m) = m + (m>>4)*2; compute read base for tx
    int pb = tx * 4 + (tx >> 2) * 2;

    // prologue: stage k-tile 0 into buf 0
    {
        double qreg[4]; double2 kreg[8]; int rr[8];
#pragma unroll
        for (int j = 0; j < 4; ++j) qreg[j] = qrow[qc + j];
#pragma unroll
        for (int s = 0; s < 8; ++s) {
            int r = krr + s * 8; rr[s] = r;
            int mrow = m0 + r;
            const double* kp = kn + (size_t)(mrow < MM ? mrow : 0) * KK + kc;
            kreg[s] = (mrow < MM) ? *(const double2*)kp : make_double2(0.0, 0.0);
        }
#pragma unroll
        for (int j = 0; j < 4; ++j) qsT[0][qc + j][qr] = qreg[j];
#pragma unroll
        for (int s = 0; s < 8; ++s) {
            int p = rr[s] + (rr[s] >> 4) * 2;
            ksT[0][kc][p]     = kreg[s].x;
            ksT[0][kc + 1][p] = kreg[s].y;
        }
    }
    __syncthreads();

    for (int t = 0; t < KK / KS; ++t) {
        int cur = t & 1;
        double qreg[4]; double2 kreg[8]; int rr[8];
        bool have = (t < KK / KS - 1);
        if (have) {                       // issue next tile's loads EARLY
            int kk2 = (t + 1) * KS;
#pragma unroll
            for (int j = 0; j < 4; ++j) qreg[j] = qrow[kk2 + qc + j];
#pragma unroll
            for (int s = 0; s < 8; ++s) {
                int r = krr + s * 8; rr[s] = r;
                int mrow = m0 + r;
                const double* kp = kn + (size_t)(mrow < MM ? mrow : 0) * KK + kk2 + kc;
                kreg[s] = (mrow < MM) ? *(const double2*)kp : make_double2(0.0, 0.0);
            }
        }
        // compute on buf cur (hides the in-flight global loads)
#pragma unroll
        for (int i = 0; i < KS; ++i) {
            double qv[4], kv[4];
            *(double2*)&qv[0] = *(const double2*)&qsT[cur][i][ty * 4];
            *(double2*)&qv[2] = *(const double2*)&qsT[cur][i][ty * 4 + 2];
            *(double2*)&kv[0] = *(const double2*)&ksT[cur][i][pb];
            *(double2*)&kv[2] = *(const double2*)&ksT[cur][i][pb + 2];
#pragma unroll
            for (int a = 0; a < 4; ++a)
#pragma unroll
                for (int c = 0; c < 4; ++c)
                    acc[a][c] += qv[a] * kv[c];
        }
        if (have) {                       // LDS writes LATE
            int nxt = cur ^ 1;
#pragma unroll
            for (int j = 0; j < 4; ++j) qsT[nxt][qc + j][qr] = qreg[j];
#pragma unroll
            for (int s = 0; s < 8; ++s) {
                int p = rr[s] + (rr[s] >> 4) * 2;
                ksT[nxt][kc][p]     = kreg[s].x;
                ksT[nxt][kc + 1][p] = kreg[s].y;
            }
        }
        __syncthreads();
    }
#pragma unroll
    for (int a = 0; a < 4; ++a) {
        int bb = b0 + ty * 4 + a;
#pragma unroll
        for (int c = 0; c < 4; ++c) {
            int mm2 = m0 + tx * 4 + c;
            if (mm2 < MM) sims[(size_t)bb * MM + mm2] = acc[a][c];
        }
    }
}

// K4: per-row top-8 (value desc, stable by index) in f64 + confidences
// (verbatim from round-2 PASSED kernel)
__global__ void k_topk(const double* __restrict__ sims, const int* __restrict__ midx,
                       const float* __restrict__ usage, float* __restrict__ out_conf,
                       float* __restrict__ out_sims, int* __restrict__ acts) {
    int b = blockIdx.x, t = threadIdx.x;
    double v[TOPK];
    int id[TOPK];
#pragma unroll
    for (int i = 0; i < TOPK; ++i) { v[i] = -INFINITY; id[i] = 0x7fffffff; }
    const double* row = sims + (size_t)b * MM;
    for (int m = t; m < MM; m += 256) {
        double x = row[m];
        if (x > v[TOPK - 1]) {
            v[TOPK - 1] = x; id[TOPK - 1] = m;
#pragma unroll
            for (int i = TOPK - 1; i > 0; --i) {
                if (v[i] > v[i - 1]) {  // strict: equal values keep smaller index first
                    double tv = v[i]; v[i] = v[i - 1]; v[i - 1] = tv;
                    int ti = id[i]; id[i] = id[i - 1]; id[i - 1] = ti;
                }
            }
        }
    }
    __shared__ double sv[256 * TOPK];
    __shared__ int si[256 * TOPK];
#pragma unroll
    for (int i = 0; i < TOPK; ++i) { sv[t * TOPK + i] = v[i]; si[t * TOPK + i] = id[i]; }
    __syncthreads();
    for (int stride = 128; stride > 0; stride >>= 1) {
        if (t < stride) {
            double* av = &sv[t * TOPK];
            int*    ai = &si[t * TOPK];
            double* bv = &sv[(t + stride) * TOPK];
            int*    bi = &si[(t + stride) * TOPK];
            double mv[TOPK]; int mi[TOPK];
            int pa = 0, pb = 0;
#pragma unroll
            for (int i = 0; i < TOPK; ++i) {
                double va = av[pa], vb = bv[pb];
                bool takeA = (va > vb) || (va == vb && ai[pa] < bi[pb]);
                if (takeA) { mv[i] = va; mi[i] = ai[pa]; ++pa; }
                else       { mv[i] = vb; mi[i] = bi[pb]; ++pb; }
            }
#pragma unroll
            for (int i = 0; i < TOPK; ++i) { av[i] = mv[i]; ai[i] = mi[i]; }
        }
        __syncthreads();
    }
    if (t < TOPK) {
        double val = sv[t];
        int idx = si[t];
        int actual = midx[idx];
        out_sims[b * TOPK + t] = (float)val;
        out_conf[b * TOPK + t] = (float)(val * (1.0 + log1p((double)usage[actual])));
        acts[b * TOPK + t] = actual;
    }
}

// K5: retrieved[b,k,v] = sum_d e[b,d] * A[acts[b,k], d, v]
// float4 loads, 4 waves split the d-range, LDS reduce.
// (verbatim from round-4 PASSED kernel)
__global__ void __launch_bounds__(256) k_retr(
        const float* __restrict__ A, const double* __restrict__ e64,
        const int* __restrict__ acts, float* __restrict__ out) {
    int bk_ = blockIdx.x;        // b*TOPK + k
    int b = bk_ >> 3;
    int tid = threadIdx.x;
    int w = tid >> 6, l = tid & 63;
    size_t n = (size_t)acts[bk_];
    const float* Ap = A + n * (size_t)(KK * VV);
    __shared__ float es[KK];
    __shared__ float part[4][64][4];
    es[tid] = (float)e64[b * KK + tid];
    __syncthreads();
    float ax = 0.f, ay = 0.f, az = 0.f, aw = 0.f;
    const float* base = Ap + (size_t)(w * 64) * VV + 4 * l;
#pragma unroll 8
    for (int dd = 0; dd < 64; ++dd) {
        float ev = es[w * 64 + dd];
        const float4 a = *reinterpret_cast<const float4*>(base + (size_t)dd * VV);
        ax = fmaf(ev, a.x, ax); ay = fmaf(ev, a.y, ay);
        az = fmaf(ev, a.z, az); aw = fmaf(ev, a.w, aw);
    }
    part[w][l][0] = ax; part[w][l][1] = ay; part[w][l][2] = az; part[w][l][3] = aw;
    __syncthreads();
    int l2 = tid >> 2, j = tid & 3;
    float s = part[0][l2][j] + part[1][l2][j] + part[2][l2][j] + part[3][l2][j];
    out[(size_t)bk_ * VV + tid] = s;   // 4*l2 + j == tid
}

extern "C" void kernel_launch(void* const* d_in, const int* in_sizes, int n_in,
                              void* d_out, int out_size, void* d_ws, size_t ws_size,
                              hipStream_t stream) {
    const float* qk    = (const float*)d_in[0];
    const float* Wk    = (const float*)d_in[1];
    const float* bk    = (const float*)d_in[2];
    const float* A     = (const float*)d_in[3];
    const float* usage = (const float*)d_in[4];
    const int*   midx  = (const int*)d_in[5];

    float* out   = (float*)d_out;
    float* retr  = out;                                 // B*TOPK*V = 524288
    float* conf  = out + (size_t)BB * TOPK * VV;        // 2048
    float* tsims = conf + BB * TOPK;                    // 2048

    // workspace layout: identical to the r2/r4 PASSED layout
    double* ws64  = (double*)d_ws;
    double* e64   = ws64;                               // 65536 doubles
    double* qn64  = e64 + BB * KK;                      // 65536
    double* kn64  = qn64 + BB * KK;                     // 1,024,000
    double* sims  = kn64 + (size_t)MM * KK;             // 1,024,000
    int*    acts  = (int*)(sims + (size_t)BB * MM);     // 2048 ints

    k_proj<<<BB, 256, 0, stream>>>(qk, Wk, bk, e64, qn64);
    k_kn<<<MM, 256, 0, stream>>>(A, midx, kn64);
    dim3 g3((MM + BNS - 1) / BNS, BB / BMS);            // 63 x 16 = 1008 blocks
    k_sims<<<g3, 64, 0, stream>>>(qn64, kn64, sims);
    k_topk<<<BB, 256, 0, stream>>>(sims, midx, usage, conf, tsims, acts);
    k_retr<<<BB * TOPK, 256, 0, stream>>>(A, e64, acts, retr);
}